// Round 2
// baseline (274.437 us; speedup 1.0000x reference)
//
#include <hip/hip_runtime.h>
#include <stdint.h>

#define K_DIM 8192
#define N_DIM 28672

typedef _Float16 half8 __attribute__((ext_vector_type(8)));
typedef _Float16 half2t __attribute__((ext_vector_type(2)));
typedef float f32x16 __attribute__((ext_vector_type(16)));

// int4 nibbles -> fp16, slot order [n0,n4,n1,n5,n2,n6,n3,n7], value = n - 8 (exact).
// 0x6400 = 1024.0h; (1024+n) - 1032 = n - 8.
static __device__ __forceinline__ half8 dq(uint32_t w) {
  const uint32_t M4 = 0x000F000Fu, E = 0x64006400u;
  half2t off; off[0] = (_Float16)(-1032.0f); off[1] = (_Float16)(-1032.0f);
  half2t v0 = __builtin_bit_cast(half2t, ( w         & M4) | E) + off;  // (n0,n4)
  half2t v1 = __builtin_bit_cast(half2t, ((w >> 4)   & M4) | E) + off;  // (n1,n5)
  half2t v2 = __builtin_bit_cast(half2t, ((w >> 8)   & M4) | E) + off;  // (n2,n6)
  half2t v3 = __builtin_bit_cast(half2t, ((w >> 12)  & M4) | E) + off;  // (n3,n7)
  half8 r;
  r[0] = v0[0]; r[1] = v0[1]; r[2] = v1[0]; r[3] = v1[1];
  r[4] = v2[0]; r[5] = v2[1]; r[6] = v3[0]; r[7] = v3[1];
  return r;
}

// One 128-k scale group: 8 MFMAs, per-group f32 scale fold, double-buffered qweight.
static __device__ __forceinline__ void group_step(
    bool prefetch, const float*& xrow, const float*& sp, const uint32_t*& qpre,
    uint32_t (&wcur)[8], uint32_t (&wnext)[8], f32x16& acc) {
  // A fragments first: 8 consecutive f32 -> 4 pk-cvt; pairing (a_j, a_{j+4})
  // matches dq's slot interleave exactly (conversion exact: values are f16 grid).
  half8 af[8];
#pragma unroll
  for (int i = 0; i < 8; i++) {
    float4 xa = *(const float4*)(xrow + 16 * i);
    float4 xb = *(const float4*)(xrow + 16 * i + 4);
    half2t p0 = __builtin_bit_cast(half2t, __builtin_amdgcn_cvt_pkrtz(xa.x, xb.x));
    half2t p1 = __builtin_bit_cast(half2t, __builtin_amdgcn_cvt_pkrtz(xa.y, xb.y));
    half2t p2 = __builtin_bit_cast(half2t, __builtin_amdgcn_cvt_pkrtz(xa.z, xb.z));
    half2t p3 = __builtin_bit_cast(half2t, __builtin_amdgcn_cvt_pkrtz(xa.w, xb.w));
    af[i][0] = p0[0]; af[i][1] = p0[1]; af[i][2] = p1[0]; af[i][3] = p1[1];
    af[i][4] = p2[0]; af[i][5] = p2[1]; af[i][6] = p3[0]; af[i][7] = p3[1];
  }
  float s = sp[0];
  if (prefetch) {
#pragma unroll
    for (int i = 0; i < 8; i++) wnext[i] = qpre[(size_t)(2 * i) * N_DIM];
    qpre += (size_t)16 * N_DIM;
  }
  f32x16 grp;
#pragma unroll
  for (int j = 0; j < 16; j++) grp[j] = 0.0f;
#pragma unroll
  for (int i = 0; i < 8; i++)
    grp = __builtin_amdgcn_mfma_f32_32x32x16_f16(af[i], dq(wcur[i]), grp, 0, 0, 0);
#pragma unroll
  for (int j = 0; j < 16; j++) acc[j] = fmaf(s, grp[j], acc[j]);
  xrow += 128;     // 16 word-rows * 8 k
  sp += N_DIM;     // next scale group
}

__global__ __launch_bounds__(256, 4) void qgemm(
    const uint32_t* __restrict__ q, const float* __restrict__ scales,
    const float* __restrict__ bias, const float* __restrict__ x,
    float* __restrict__ out) {
  __shared__ float red[4][32][32];
  const int tid  = threadIdx.x;
  const int wave = tid >> 6;
  const int lane = tid & 63;
  const int h    = lane >> 5;
  const int nl   = lane & 31;
  const int col0 = blockIdx.x << 5;

  const int k8_0 = wave << 8;   // 256 qweight word-rows per wave (K/4)
  const int g0   = wave << 4;   // 16 scale groups per wave

  const uint32_t* qcur = q + (size_t)(k8_0 + h) * N_DIM + col0 + nl;
  const float*    xrow = x + (size_t)nl * K_DIM + (size_t)(k8_0 + h) * 8;
  const float*    sp   = scales + (size_t)g0 * N_DIM + col0 + nl;

  f32x16 acc;
#pragma unroll
  for (int j = 0; j < 16; j++) acc[j] = 0.0f;

  uint32_t wA[8], wB[8];
#pragma unroll
  for (int i = 0; i < 8; i++) wA[i] = qcur[(size_t)(2 * i) * N_DIM];
  const uint32_t* qpre = qcur + (size_t)16 * N_DIM;

  for (int gg = 0; gg < 8; ++gg) {
    group_step(true,    xrow, sp, qpre, wA, wB, acc);
    group_step(gg < 7,  xrow, sp, qpre, wB, wA, acc);
  }

  // C/D layout (32x32): col = lane&31, row = (reg&3) + 8*(reg>>2) + 4*(lane>>5)
#pragma unroll
  for (int j = 0; j < 16; j++) {
    int row = (j & 3) + ((j >> 2) << 3) + (h << 2);
    red[wave][row][nl] = acc[j];
  }
  __syncthreads();

  const int col = tid & 31;
  const int r0  = tid >> 5;   // 0..7
#pragma unroll
  for (int i = 0; i < 4; i++) {
    int row = r0 + (i << 3);
    float v = red[0][row][col] + red[1][row][col] +
              red[2][row][col] + red[3][row][col];
    v += bias[col0 + col];
    out[(size_t)row * N_DIM + col0 + col] = v;
  }
}

extern "C" void kernel_launch(void* const* d_in, const int* in_sizes, int n_in,
                              void* d_out, int out_size, void* d_ws, size_t ws_size,
                              hipStream_t stream) {
  const float*    xf      = (const float*)d_in[0];
  const uint32_t* qweight = (const uint32_t*)d_in[1];
  const float*    scales  = (const float*)d_in[2];
  const float*    bias    = (const float*)d_in[3];
  float*          out     = (float*)d_out;
  (void)d_ws; (void)ws_size; (void)in_sizes; (void)n_in;

  qgemm<<<dim3(N_DIM / 32), dim3(256), 0, stream>>>(qweight, scales, bias, xf, out);
}

// Round 3
// 212.944 us; speedup vs baseline: 1.2888x; 1.2888x over previous
//
#include <hip/hip_runtime.h>
#include <stdint.h>

#define K_DIM 8192
#define N_DIM 28672

typedef _Float16 half8 __attribute__((ext_vector_type(8)));
typedef _Float16 half2t __attribute__((ext_vector_type(2)));
typedef float f32x16 __attribute__((ext_vector_type(16)));

// ---- prep: x f32 [32][8192] -> xp f16 [K/8][32][8] in A-fragment slot order
// slot order per 8-k word: [k0,k4,k1,k5,k2,k6,k3,k7] (matches dq nibble interleave)
__global__ __launch_bounds__(256) void prep_x(const float* __restrict__ x,
                                              _Float16* __restrict__ xp) {
  int idx = blockIdx.x * 256 + threadIdx.x;  // 32768 = 1024 word-rows * 32 m
  int m  = idx & 31;
  int k8 = idx >> 5;
  const float* p = x + (size_t)m * K_DIM + (size_t)k8 * 8;
  float4 xa = *(const float4*)p;
  float4 xb = *(const float4*)(p + 4);
  // pairing (x_j, x_{j+4}); conversion exact (values lie on f16 grid)
  half2t p0 = __builtin_bit_cast(half2t, __builtin_amdgcn_cvt_pkrtz(xa.x, xb.x));
  half2t p1 = __builtin_bit_cast(half2t, __builtin_amdgcn_cvt_pkrtz(xa.y, xb.y));
  half2t p2 = __builtin_bit_cast(half2t, __builtin_amdgcn_cvt_pkrtz(xa.z, xb.z));
  half2t p3 = __builtin_bit_cast(half2t, __builtin_amdgcn_cvt_pkrtz(xa.w, xb.w));
  half8 o;
  o[0] = p0[0]; o[1] = p0[1]; o[2] = p1[0]; o[3] = p1[1];
  o[4] = p2[0]; o[5] = p2[1]; o[6] = p3[0]; o[7] = p3[1];
  *(half8*)(xp + ((size_t)k8 * 32 + m) * 8) = o;
}

// int4 word -> 8 f16 in slots [n0,n4,n1,n5,n2,n6,n3,n7], value (n-8)*s.
// (1024+n)-1032 is exact in f16; (n-8)*s single-rounds like the reference.
static __device__ __forceinline__ half8 dqs(uint32_t w, half2t sh) {
  const uint32_t M4 = 0x000F000Fu, E = 0x64006400u;
  half2t off; off[0] = (_Float16)(-1032.0f); off[1] = (_Float16)(-1032.0f);
  half2t v0 = (__builtin_bit_cast(half2t, ( w        & M4) | E) + off) * sh;
  half2t v1 = (__builtin_bit_cast(half2t, ((w >> 4)  & M4) | E) + off) * sh;
  half2t v2 = (__builtin_bit_cast(half2t, ((w >> 8)  & M4) | E) + off) * sh;
  half2t v3 = (__builtin_bit_cast(half2t, ((w >> 12) & M4) | E) + off) * sh;
  half8 r;
  r[0] = v0[0]; r[1] = v0[1]; r[2] = v1[0]; r[3] = v1[1];
  r[4] = v2[0]; r[5] = v2[1]; r[6] = v3[0]; r[7] = v3[1];
  return r;
}

// One 128-k scale group: 8 MFMAs accumulate straight into acc (scale folded
// into B in f16), depth-1 qweight prefetch for the following group.
static __device__ __forceinline__ void group_step(
    bool prefetch, const _Float16*& ap, const float*& sp, const uint32_t*& qpre,
    uint32_t (&wcur)[8], uint32_t (&wnext)[8], f32x16& acc) {
  half8 af[8];
#pragma unroll
  for (int i = 0; i < 8; i++)
    af[i] = *(const half8*)(ap + (size_t)(2 * i) * 256);  // +1024B each, imm offsets
  float s = sp[0];
  half2t sh = __builtin_bit_cast(half2t, __builtin_amdgcn_cvt_pkrtz(s, s));
  if (prefetch) {
#pragma unroll
    for (int i = 0; i < 8; i++) wnext[i] = qpre[(size_t)(2 * i) * N_DIM];
    qpre += (size_t)16 * N_DIM;
  }
#pragma unroll
  for (int i = 0; i < 8; i++)
    acc = __builtin_amdgcn_mfma_f32_32x32x16_f16(af[i], dqs(wcur[i], sh), acc, 0, 0, 0);
  ap += (size_t)16 * 256;   // 16 word-rows
  sp += N_DIM;
}

__global__ __launch_bounds__(512, 6) void qgemm(
    const uint32_t* __restrict__ q, const float* __restrict__ scales,
    const float* __restrict__ bias, const _Float16* __restrict__ xp,
    float* __restrict__ out) {
  __shared__ float red[8][32][32];   // 32 KB
  const int tid  = threadIdx.x;
  const int wave = tid >> 6;         // 0..7 : 8-way split-K
  const int lane = tid & 63;
  const int h    = lane >> 5;
  const int nl   = lane & 31;
  const int col0 = blockIdx.x << 5;

  const int wr0 = wave << 7;         // 128 word-rows (1024 k) per wave

  const uint32_t* qcur = q + (size_t)(wr0 + h) * N_DIM + col0 + nl;
  const _Float16* ap   = xp + ((size_t)(wr0 + h) * 32 + nl) * 8;
  const float*    sp   = scales + (size_t)(wave << 3) * N_DIM + col0 + nl;

  f32x16 acc;
#pragma unroll
  for (int j = 0; j < 16; j++) acc[j] = 0.0f;

  uint32_t wA[8], wB[8];
#pragma unroll
  for (int i = 0; i < 8; i++) wA[i] = qcur[(size_t)(2 * i) * N_DIM];
  const uint32_t* qpre = qcur + (size_t)16 * N_DIM;

  for (int gg = 0; gg < 4; ++gg) {
    group_step(true,    ap, sp, qpre, wA, wB, acc);
    group_step(gg < 3,  ap, sp, qpre, wB, wA, acc);
  }

  // C/D layout (32x32): col = lane&31, row = (reg&3) + 8*(reg>>2) + 4*(lane>>5)
#pragma unroll
  for (int j = 0; j < 16; j++) {
    int row = (j & 3) + ((j >> 2) << 3) + (h << 2);
    red[wave][row][nl] = acc[j];
  }
  __syncthreads();

  const int col = tid & 31;
  const int r0  = tid >> 5;          // 0..15
#pragma unroll
  for (int i = 0; i < 2; i++) {
    int row = r0 + (i << 4);
    float v = 0.0f;
#pragma unroll
    for (int w = 0; w < 8; w++) v += red[w][row][col];
    v += bias[col0 + col];
    out[(size_t)row * N_DIM + col0 + col] = v;
  }
}

extern "C" void kernel_launch(void* const* d_in, const int* in_sizes, int n_in,
                              void* d_out, int out_size, void* d_ws, size_t ws_size,
                              hipStream_t stream) {
  const float*    xf      = (const float*)d_in[0];
  const uint32_t* qweight = (const uint32_t*)d_in[1];
  const float*    scales  = (const float*)d_in[2];
  const float*    bias    = (const float*)d_in[3];
  float*          out     = (float*)d_out;
  _Float16*       xp      = (_Float16*)d_ws;   // 512 KB scratch

  prep_x<<<dim3(128), dim3(256), 0, stream>>>(xf, xp);
  qgemm<<<dim3(N_DIM / 32), dim3(512), 0, stream>>>(qweight, scales, bias, xp, out);
}

// Round 4
// 189.529 us; speedup vs baseline: 1.4480x; 1.1235x over previous
//
#include <hip/hip_runtime.h>
#include <stdint.h>

#define K_DIM 8192
#define N_DIM 28672

typedef _Float16 half8 __attribute__((ext_vector_type(8)));
typedef _Float16 half2t __attribute__((ext_vector_type(2)));
typedef float f32x16 __attribute__((ext_vector_type(16)));

// ---- prep: x f32 [32][8192] -> xp f16 [K/8][32][8] in A-fragment slot order
__global__ __launch_bounds__(256) void prep_x(const float* __restrict__ x,
                                              _Float16* __restrict__ xp) {
  int idx = blockIdx.x * 256 + threadIdx.x;  // 32768 = 1024 word-rows * 32 m
  int m  = idx & 31;
  int k8 = idx >> 5;
  const float* p = x + (size_t)m * K_DIM + (size_t)k8 * 8;
  float4 xa = *(const float4*)p;
  float4 xb = *(const float4*)(p + 4);
  half2t p0 = __builtin_bit_cast(half2t, __builtin_amdgcn_cvt_pkrtz(xa.x, xb.x));
  half2t p1 = __builtin_bit_cast(half2t, __builtin_amdgcn_cvt_pkrtz(xa.y, xb.y));
  half2t p2 = __builtin_bit_cast(half2t, __builtin_amdgcn_cvt_pkrtz(xa.z, xb.z));
  half2t p3 = __builtin_bit_cast(half2t, __builtin_amdgcn_cvt_pkrtz(xa.w, xb.w));
  half8 o;
  o[0] = p0[0]; o[1] = p0[1]; o[2] = p1[0]; o[3] = p1[1];
  o[4] = p2[0]; o[5] = p2[1]; o[6] = p3[0]; o[7] = p3[1];
  *(half8*)(xp + ((size_t)k8 * 32 + m) * 8) = o;
}

__global__ __launch_bounds__(256) void zero_out(float4* __restrict__ out) {
  out[(size_t)blockIdx.x * 256 + threadIdx.x] = float4{0.f, 0.f, 0.f, 0.f};
}

// int4 word -> 8 f16 slots [n0,n4,n1,n5,n2,n6,n3,n7], value (n-8)*s (exact add)
static __device__ __forceinline__ half8 dqs(uint32_t w, half2t sh) {
  const uint32_t M4 = 0x000F000Fu, E = 0x64006400u;
  half2t off; off[0] = (_Float16)(-1032.0f); off[1] = (_Float16)(-1032.0f);
  half2t v0 = (__builtin_bit_cast(half2t, ( w        & M4) | E) + off) * sh;
  half2t v1 = (__builtin_bit_cast(half2t, ((w >> 4)  & M4) | E) + off) * sh;
  half2t v2 = (__builtin_bit_cast(half2t, ((w >> 8)  & M4) | E) + off) * sh;
  half2t v3 = (__builtin_bit_cast(half2t, ((w >> 12) & M4) | E) + off) * sh;
  half8 r;
  r[0] = v0[0]; r[1] = v0[1]; r[2] = v1[0]; r[3] = v1[1];
  r[4] = v2[0]; r[5] = v2[1]; r[6] = v3[0]; r[7] = v3[1];
  return r;
}

static __device__ __forceinline__ void gl_lds16(const void* g, void* l) {
  __builtin_amdgcn_global_load_lds(
      (const __attribute__((address_space(1))) uint32_t*)g,
      (__attribute__((address_space(3))) uint32_t*)l, 16, 0, 0);
}

// wait until <= n VMEM ops outstanding (exp=7, lgkm=15 => no wait on those)
static __device__ __forceinline__ void waitcnt_vm(int n) {
  switch (n) {
    case 0: __builtin_amdgcn_s_waitcnt(0x0F70); break;
    case 4: __builtin_amdgcn_s_waitcnt(0x0F74); break;
    default: __builtin_amdgcn_s_waitcnt(0x0F78); break;  // 8
  }
}

// Block: 256 thr = 4 waves; tile = 128 cols x 1024 k (8 groups of 128k).
// Grid split-K x8 -> f32 atomic accumulation into out.
// LDS: 3 pipeline stages x (A 8KB + Q 8KB) = 48KB.
__global__ __launch_bounds__(256, 4) void qgemm(
    const uint32_t* __restrict__ q, const float* __restrict__ scales,
    const float* __restrict__ bias, const _Float16* __restrict__ xp,
    float* __restrict__ out) {
  __shared__ __attribute__((aligned(16))) char smem[3 * 16384];
  const int tid  = threadIdx.x;
  const int w    = tid >> 6;
  const int lane = tid & 63;
  const int h    = lane >> 5;
  const int nl   = lane & 31;
  const int bid  = blockIdx.x;
  const int kblk = bid & 7;
  const int col0 = (bid >> 3) << 7;     // 128-col tile
  const int wr0  = kblk << 7;           // first word-row of K-slice
  const int colw = col0 + (w << 5);     // wave's 32-col base

  // Preload + convert all 8 group scales BEFORE staging, so the vmcnt queue
  // contains only stage DMA during the pipelined loop.
  half2t sh[8];
#pragma unroll
  for (int g = 0; g < 8; g++) {
    float s = scales[(size_t)(kblk * 8 + g) * N_DIM + colw + nl];
    sh[g] = __builtin_bit_cast(half2t, __builtin_amdgcn_cvt_pkrtz(s, s));
  }

  const char* xb = (const char*)xp;
  // stage group g into buffer g%3: 4 global_load_lds per wave (16/block)
  auto stage = [&](int g) {
    char* A = smem + (g % 3) * 16384;
    char* Q = A + 8192;
    size_t ga = (size_t)(wr0 + 16 * g) * 512 + (size_t)w * 2048 + (size_t)lane * 16;
#pragma unroll
    for (int j = 0; j < 2; j++)
      gl_lds16(xb + ga + j * 1024, A + w * 2048 + j * 1024);
#pragma unroll
    for (int j = 0; j < 2; j++) {
      int row = wr0 + 16 * g + 4 * w + 2 * j + h;
      gl_lds16(q + (size_t)row * N_DIM + col0 + nl * 4, Q + (4 * w + 2 * j) * 512);
    }
  };

  f32x16 acc;
#pragma unroll
  for (int j = 0; j < 16; j++) acc[j] = 0.0f;

  stage(0); stage(1); stage(2);

#pragma unroll
  for (int g = 0; g < 8; g++) {
    // own stage-g DMA done (keep 2 newest stages in flight — never vmcnt(0))
    waitcnt_vm(g <= 5 ? 8 : (g == 6 ? 4 : 0));
    __builtin_amdgcn_s_barrier();       // all waves' stage-g visible
    const char* A = smem + (g % 3) * 16384;
    const char* Q = A + 8192;
    half2t s = sh[g];
#pragma unroll
    for (int i = 0; i < 8; i++) {
      half8 af = *(const half8*)(A + (size_t)((2 * i + h) * 32 + nl) * 16);
      uint32_t wq = *(const uint32_t*)(Q + (2 * i + h) * 512 + (w * 32 + nl) * 4);
      acc = __builtin_amdgcn_mfma_f32_32x32x16_f16(af, dqs(wq, s), acc, 0, 0, 0);
    }
    __builtin_amdgcn_s_barrier();       // buffer g%3 free for overwrite
    if (g + 3 < 8) stage(g + 3);
  }

  // epilogue: C/D 32x32 layout col=lane&31, row=(reg&3)+8*(reg>>2)+4*(lane>>5)
  float bs = (kblk == 0) ? bias[colw + nl] : 0.0f;
#pragma unroll
  for (int j = 0; j < 16; j++) {
    int row = (j & 3) + ((j >> 2) << 3) + (h << 2);
    unsafeAtomicAdd(&out[(size_t)row * N_DIM + colw + nl], acc[j] + bs);
  }
}

extern "C" void kernel_launch(void* const* d_in, const int* in_sizes, int n_in,
                              void* d_out, int out_size, void* d_ws, size_t ws_size,
                              hipStream_t stream) {
  const float*    xf      = (const float*)d_in[0];
  const uint32_t* qweight = (const uint32_t*)d_in[1];
  const float*    scales  = (const float*)d_in[2];
  const float*    bias    = (const float*)d_in[3];
  float*          out     = (float*)d_out;
  _Float16*       xp      = (_Float16*)d_ws;   // 512 KB scratch

  zero_out<<<dim3(896), dim3(256), 0, stream>>>((float4*)out);
  prep_x<<<dim3(128), dim3(256), 0, stream>>>(xf, xp);
  qgemm<<<dim3((N_DIM / 128) * 8), dim3(256), 0, stream>>>(qweight, scales, bias, xp, out);
}